// Round 5
// baseline (654.170 us; speedup 1.0000x reference)
//
#include <hip/hip_runtime.h>
#include <float.h>
#include <math.h>

#define NN 8192
#define DH 256
#define KNN 10
#define TSTEPS 10
#define EPSC 0.1f
#define CTILE 1024          // candidates staged in LDS per tile
#define QPB 16              // queries per block (16 waves of 64)

typedef short s8v __attribute__((ext_vector_type(8)));
typedef float f4v __attribute__((ext_vector_type(4)));

__device__ __forceinline__ float bf2f(unsigned short u) {
    union { unsigned u; float f; } c; c.u = ((unsigned)u) << 16; return c.f;
}
__device__ __forceinline__ unsigned short f2bf(float f) {
    union { float f; unsigned u; } c; c.f = f;
    unsigned r = c.u + 0x7FFF + ((c.u >> 16) & 1);
    return (unsigned short)(r >> 16);
}

// Wave-uniform top-10 kept as UNSIGNED DISTANCE BITS (IEEE order == uint order
// for non-negative floats). All values derive from readlane/ballot -> uniform
// -> the bubble network lives on the SCALAR pipe, co-issuing with VALU.
// ~86us SALU floor at 1 scalar unit/CU; measured 123us. Parked.
#define DECL_TOP10U \
    unsigned b0=0x7F7FFFFFu,b1=0x7F7FFFFFu,b2=0x7F7FFFFFu,b3=0x7F7FFFFFu, \
             b4=0x7F7FFFFFu,b5=0x7F7FFFFFu,b6=0x7F7FFFFFu,b7=0x7F7FFFFFu, \
             b8=0x7F7FFFFFu,b9=0x7F7FFFFFu; \
    int i0=-1,i1=-1,i2=-1,i3=-1,i4=-1,i5=-1,i6=-1,i7=-1,i8=-1,i9=-1;

#define BSTEPU(bk, ik) { \
    bool     _s  = _tu < bk; \
    unsigned _bn = _s ? _tu : bk; \
    _tu          = _s ? bk : _tu; \
    int      _in = _s ? _it : ik; \
    _it          = _s ? ik : _it; \
    bk = _bn; ik = _in; \
}

#define BUBBLE10U(dv, jv) do { \
    unsigned _tu = (dv); int _it = (jv); \
    BSTEPU(b0, i0) BSTEPU(b1, i1) BSTEPU(b2, i2) BSTEPU(b3, i3) BSTEPU(b4, i4) \
    BSTEPU(b5, i5) BSTEPU(b6, i6) BSTEPU(b7, i7) BSTEPU(b8, i8) BSTEPU(b9, i9) \
} while (0)

// ---------------- conv_ws [3][256][256] (k,n) -> bf16 Wt [3][n][k] ------------
__global__ void prep_wt(const float* __restrict__ W, unsigned short* __restrict__ Wt) {
    int e = blockIdx.x * 256 + threadIdx.x;
    int g = e >> 16; int rem = e & 65535;
    int n = rem >> 8; int k = rem & 255;
    Wt[e] = f2bf(W[g * 65536 + k * 256 + n]);
}

// ---------------- pos4[j] = {x, y, z, |p|^2} ----------------------------------
__global__ void prep_pos(const float* __restrict__ pos, float4* __restrict__ pos4) {
    int j = blockIdx.x * 256 + threadIdx.x;
    float x = pos[j * 3], y = pos[j * 3 + 1], z = pos[j * 3 + 2];
    float4 v; v.x = x; v.y = y; v.z = z; v.w = x * x + y * y + z * z;
    pos4[j] = v;
}

// ---------------- kNN: 1 wave/query, 16 queries/block, scalar-pipe inserts ----
__launch_bounds__(1024)
__global__ void knn_wave(const float* __restrict__ pos, const float4* __restrict__ pos4,
                         int* __restrict__ nbr) {
    __shared__ float4 cand[CTILE];
    int tid = threadIdx.x;
    int wv = tid >> 6, lane = tid & 63;
    int i = blockIdx.x * QPB + wv;               // query for this wave
    float xi = pos[i * 3], yi = pos[i * 3 + 1], zi = pos[i * 3 + 2];
    float sqi = xi * xi + yi * yi + zi * zi;
    int igrp = i & ~63;                          // the only 64-group containing i

    DECL_TOP10U;

    for (int tile = 0; tile < NN / CTILE; ++tile) {
        __syncthreads();
        cand[tid] = pos4[tile * CTILE + tid];    // 1024 threads, 1 float4 each
        __syncthreads();
#pragma unroll 4
        for (int u = 0; u < CTILE / 64; ++u) {
            int jgrp = tile * CTILE + u * 64;
            float4 c = cand[u * 64 + lane];
            int j = jgrp + lane;
            float m = c.x * xi + c.y * yi + c.z * zi;
            float d = (sqi + c.w) - 2.0f * m;
            d = fmaxf(d, 0.0f);                  // uint-order safety (rounding)
            if (jgrp == igrp) {                  // wave-uniform branch
                if (j == i) d = FLT_MAX;         // self-exclusion, one batch only
            }
            unsigned du = __float_as_uint(d);
            unsigned long long mask = __ballot(du < b9);
            while (mask) {
                int l = __ffsll(mask) - 1;
                mask &= mask - 1;
                unsigned dcu = (unsigned)__builtin_amdgcn_readlane((int)du, l);
                if (dcu < b9) {                  // recheck vs updated threshold
                    int jc = __builtin_amdgcn_readlane(j, l);
                    BUBBLE10U(dcu, jc);
                }
            }
        }
    }

    // rank 'lane' index via cndmask ladder (runs once)
    int jv = i0;
    jv = (lane >= 1) ? i1 : jv;
    jv = (lane >= 2) ? i2 : jv;
    jv = (lane >= 3) ? i3 : jv;
    jv = (lane >= 4) ? i4 : jv;
    jv = (lane >= 5) ? i5 : jv;
    jv = (lane >= 6) ? i6 : jv;
    jv = (lane >= 7) ? i7 : jv;
    jv = (lane >= 8) ? i8 : jv;
    jv = (lane >= 9) ? i9 : jv;
    if (lane < KNN) nbr[i * KNN + lane] = jv;
}

// ---------------- h = lm@emb_w + emb_b ; x = h@rw + rb ------------------------
__global__ void emb_kernel(const float* __restrict__ lm, const float* __restrict__ ew,
                           const float* __restrict__ eb, const float* __restrict__ rw,
                           const float* __restrict__ rb,
                           float* __restrict__ hdo, unsigned short* __restrict__ hbf,
                           float* __restrict__ xout) {
    __shared__ float s0[4], s1[4], s2[4];
    int i = blockIdx.x, d = threadIdx.x;
    float a0 = lm[i * 3], a1 = lm[i * 3 + 1], a2 = lm[i * 3 + 2];
    float h = eb[d] + a0 * ew[d] + a1 * ew[256 + d] + a2 * ew[512 + d];
    hdo[i * 256 + d] = h;
    hbf[i * 256 + d] = f2bf(h);
    float p0 = h * rw[d * 3], p1 = h * rw[d * 3 + 1], p2 = h * rw[d * 3 + 2];
    for (int off = 32; off; off >>= 1) {
        p0 += __shfl_down(p0, off, 64);
        p1 += __shfl_down(p1, off, 64);
        p2 += __shfl_down(p2, off, 64);
    }
    int lane = d & 63, wid = d >> 6;
    if (lane == 0) { s0[wid] = p0; s1[wid] = p1; s2[wid] = p2; }
    __syncthreads();
    if (d == 0) {
        xout[i * 3 + 0] = s0[0] + s0[1] + s0[2] + s0[3] + rb[0];
        xout[i * 3 + 1] = s1[0] + s1[1] + s1[2] + s1[3] + rb[1];
        xout[i * 3 + 2] = s2[0] + s2[1] + s2[2] + s2[3] + rb[2];
    }
}

// ---------------- hop-1: x1[i] = 0.1 * sum_{j in nbr(i)} hbf[j] ---------------
__global__ void agg_kernel(const unsigned short* __restrict__ src,
                           unsigned short* __restrict__ dst,
                           const int* __restrict__ nbr) {
    int tid = threadIdx.x;
    int wid = tid >> 6, lane = tid & 63;
    int node = blockIdx.x * 4 + wid;
    int d0 = lane * 4;
    float a0 = 0.f, a1 = 0.f, a2 = 0.f, a3 = 0.f;
    const int* nb = nbr + node * KNN;
    for (int q = 0; q < KNN; q++) {
        int j = nb[q];
        uint2 v = *(const uint2*)(src + j * 256 + d0);
        a0 += bf2f((unsigned short)(v.x & 0xffff));
        a1 += bf2f((unsigned short)(v.x >> 16));
        a2 += bf2f((unsigned short)(v.y & 0xffff));
        a3 += bf2f((unsigned short)(v.y >> 16));
    }
    uint2 o;
    o.x = (unsigned)f2bf(a0 * 0.1f) | ((unsigned)f2bf(a1 * 0.1f) << 16);
    o.y = (unsigned)f2bf(a2 * 0.1f) | ((unsigned)f2bf(a3 * 0.1f) << 16);
    *(uint2*)(dst + node * 256 + d0) = o;
}

// ------- fused: hop-2 gather + BARRIER-FREE GEMM + Euler + readout ------------
// All GEMM operands are L2-resident (Wt 384KB, hbf 4MB, x1 4MB): A/B MFMA
// fragments are loaded DIRECTLY from global (L2-hit), no LDS staging, no
// per-K barriers. Two barriers total: after the X2 gather LDS write, and for
// the y-reduction. 512 threads = 8 waves; wave w owns cols [w*32, w*32+32) of
// a 16-row M-tile. K order 0..767 ascending (bit-identical to staged version).
__launch_bounds__(512)
__global__ void gemm_step(unsigned short* hbf,
                          const unsigned short* __restrict__ x1,
                          const int* __restrict__ nbr,
                          const unsigned short* __restrict__ Wt,
                          const float* __restrict__ cb,
                          const float* __restrict__ rw, const float* __restrict__ rb,
                          float* hdo, float* __restrict__ yout, float* yfin) {
    __shared__ __align__(16) short X2[16 * 264];
    __shared__ float rwl[768];
    __shared__ float cbl[256];
    __shared__ float yred[8][4][4][3];     // [wave][quad][r][xyz]

    int tid = threadIdx.x;
    int m0 = blockIdx.x * 16;
    for (int idx = tid; idx < 768; idx += 512) rwl[idx] = rw[idx];
    if (tid < 256) cbl[tid] = cb[tid];

    int w = tid >> 6, lane = tid & 63;
    int quad = lane >> 4, l15 = lane & 15;

    // ---- hop-2 gather: X2[row][:] = bf16(0.1 * sum x1[nbr[row]]) -------------
    // 512 threads: 32 threads/row, 8 dims (one uint4) each.
    {
        int row = tid >> 5, cg = tid & 31;
        const int* nb = nbr + (m0 + row) * KNN;
        float a[8];
#pragma unroll
        for (int e = 0; e < 8; e++) a[e] = 0.f;
        for (int q = 0; q < KNN; q++) {
            int j = nb[q];
            uint4 v = *(const uint4*)(x1 + j * 256 + cg * 8);
            a[0] += bf2f((unsigned short)(v.x & 0xffff));
            a[1] += bf2f((unsigned short)(v.x >> 16));
            a[2] += bf2f((unsigned short)(v.y & 0xffff));
            a[3] += bf2f((unsigned short)(v.y >> 16));
            a[4] += bf2f((unsigned short)(v.z & 0xffff));
            a[5] += bf2f((unsigned short)(v.z >> 16));
            a[6] += bf2f((unsigned short)(v.w & 0xffff));
            a[7] += bf2f((unsigned short)(v.w >> 16));
        }
        uint4 o;
        o.x = (unsigned)f2bf(a[0]*0.1f) | ((unsigned)f2bf(a[1]*0.1f) << 16);
        o.y = (unsigned)f2bf(a[2]*0.1f) | ((unsigned)f2bf(a[3]*0.1f) << 16);
        o.z = (unsigned)f2bf(a[4]*0.1f) | ((unsigned)f2bf(a[5]*0.1f) << 16);
        o.w = (unsigned)f2bf(a[6]*0.1f) | ((unsigned)f2bf(a[7]*0.1f) << 16);
        *(uint4*)((unsigned short*)&X2[row * 264 + cg * 8]) = o;
    }

    f4v acc[2];
    acc[0] = (f4v){0.f, 0.f, 0.f, 0.f};
    acc[1] = (f4v){0.f, 0.f, 0.f, 0.f};

    // ---- K chunks 0..15: A from hbf (K 0..255) then x1 (K 256..511) ----------
#pragma unroll
    for (int kc = 0; kc < 16; kc++) {
        const unsigned short* asrc = (kc < 8) ? (const unsigned short*)hbf : x1;
        int k = (kc & 7) * 32 + quad * 8;
        s8v a = *(const s8v*)(asrc + (m0 + l15) * 256 + k);
#pragma unroll
        for (int f = 0; f < 2; f++) {
            int n = w * 32 + f * 16 + l15;
            s8v b = *(const s8v*)(Wt + ((kc >> 3) * 256 + n) * 256 + k);
            acc[f] = __builtin_amdgcn_mfma_f32_16x16x32_bf16(a, b, acc[f], 0, 0, 0);
        }
    }

    __syncthreads();   // X2 ready

    // ---- K chunks 16..23: A from X2 in LDS (K 512..767) ----------------------
#pragma unroll
    for (int kc = 0; kc < 8; kc++) {
        int k = kc * 32 + quad * 8;
        s8v a = *(const s8v*)(&X2[l15 * 264 + k]);
#pragma unroll
        for (int f = 0; f < 2; f++) {
            int n = w * 32 + f * 16 + l15;
            s8v b = *(const s8v*)(Wt + ((2 * 256 + n) * 256) + k);
            acc[f] = __builtin_amdgcn_mfma_f32_16x16x32_bf16(a, b, acc[f], 0, 0, 0);
        }
    }

    // ---- epilogue: Euler update + readout partials ---------------------------
    float py[4][3] = {};
#pragma unroll
    for (int f = 0; f < 2; f++) {
        int col = w * 32 + f * 16 + l15;
        float cbv = cbl[col];
        float rw0 = rwl[col * 3], rw1 = rwl[col * 3 + 1], rw2 = rwl[col * 3 + 2];
#pragma unroll
        for (int r = 0; r < 4; r++) {
            int grow = m0 + quad * 4 + r;
            float cval = acc[f][r] + cbv;
            float hn = hdo[grow * 256 + col] + EPSC * tanhf(cval);
            hdo[grow * 256 + col] = hn;
            hbf[grow * 256 + col] = f2bf(hn);
            py[r][0] += hn * rw0; py[r][1] += hn * rw1; py[r][2] += hn * rw2;
        }
    }
    for (int off = 1; off < 16; off <<= 1)
        for (int r = 0; r < 4; r++)
            for (int j = 0; j < 3; j++)
                py[r][j] += __shfl_xor(py[r][j], off, 64);
    if (l15 == 0)
        for (int r = 0; r < 4; r++)
            for (int j = 0; j < 3; j++)
                yred[w][quad][r][j] = py[r][j];
    __syncthreads();
    if (w == 0 && l15 == 0) {
        for (int r = 0; r < 4; r++) {
            int grow = m0 + quad * 4 + r;
            for (int j = 0; j < 3; j++) {
                float yv = yred[0][quad][r][j] + yred[1][quad][r][j]
                         + yred[2][quad][r][j] + yred[3][quad][r][j]
                         + yred[4][quad][r][j] + yred[5][quad][r][j]
                         + yred[6][quad][r][j] + yred[7][quad][r][j] + rb[j];
                yout[grow * 3 + j] = yv;
                if (yfin) yfin[grow * 3 + j] = yv;
            }
        }
    }
}

extern "C" void kernel_launch(void* const* d_in, const int* in_sizes, int n_in,
                              void* d_out, int out_size, void* d_ws, size_t ws_size,
                              hipStream_t stream) {
    const float* lm = (const float*)d_in[0];
    const float* ew = (const float*)d_in[1];
    const float* eb = (const float*)d_in[2];
    const float* rw = (const float*)d_in[3];
    const float* rb = (const float*)d_in[4];
    const float* cw = (const float*)d_in[5];
    const float* cb = (const float*)d_in[6];

    float* out = (float*)d_out;
    float* y_out = out;
    float* h_out = out + 24576;
    float* x_out = out + 24576 + 2097152;
    float* lp_out = x_out + 24576;

    char* ws = (char*)d_ws;
    int* nbr = (int*)ws;                       ws += NN * KNN * sizeof(int);
    float4* pos4 = (float4*)ws;                ws += NN * sizeof(float4);
    char* uni = ws;
    unsigned short* hbf = (unsigned short*)uni;
    unsigned short* x1  = hbf + NN * DH;
    unsigned short* Wt  = x1 + NN * DH;

    prep_pos<<<NN / 256, 256, 0, stream>>>(lm, pos4);
    knn_wave<<<NN / QPB, 1024, 0, stream>>>(lm, pos4, nbr);
    prep_wt<<<768, 256, 0, stream>>>(cw, Wt);
    emb_kernel<<<NN, 256, 0, stream>>>(lm, ew, eb, rw, rb, h_out, hbf, x_out);
    for (int t = 0; t < TSTEPS; t++) {
        agg_kernel<<<NN / 4, 256, 0, stream>>>(hbf, x1, nbr);
        gemm_step<<<NN / 16, 512, 0, stream>>>(hbf, x1, nbr, Wt, cb, rw, rb, h_out,
                                               lp_out + t * 24576,
                                               (t == TSTEPS - 1) ? y_out : nullptr);
    }
}